// Round 8
// baseline (1138.943 us; speedup 1.0000x reference)
//
#include <hip/hip_runtime.h>

// SNN: 3-layer LIF, B=256, T=32, H=1024, IN=2312, OUT=10.
// r2 G1 (fp16 2-plane 3-pass, 128^2, 512thr, LDW=36, 2blk/CU) = 153us, 62%
//   of LDS floor at 16 waves/CU -- best measured. r6/r7 restructures (8
//   waves/CU) all ~35% util: pipe util tracks waves/CU, floors don't move.
// Round-11: raise residency on the UNCHANGED r2 inner loop via split-K2:
//   grid dim3(64,2,8) = 1024 blocks -> 4 blk/CU = 32 waves/CU (LDS 36.8KB
//   and VGPR<=64 both allow 4). K-halves combine by atomicAdd onto zeroed
//   bufI: exactly 2 IEEE-commutative adds per output => deterministic.
//   Bias added by the kz==0 contribution only. mblk-fast + z-inside keeps
//   each nblk's 2.42MB B slice XCD-L2-pinned (r6-proven).
//   GEMM2: same split-K2 structure, fp16 2-plane 2-pass (a(b0+b1), exact),
//   LDS 27.6KB. launch_bounds(512,8) pins VGPR<=64 (r2 used 52).

#define TB 256
#define TT 32
#define TH 1024
#define TIN 2312
#define TOUT 10
#define TM (TT * TB)   // 8192 rows = (t,b)
#define KP1 2368       // TIN padded to multiple of 32 (74 tiles; 37/z)
#define LDW 36         // 32 + 4 pad (r2-verified: frag reads ~2-way, free)

typedef _Float16 f16_t;
typedef f16_t f16x8 __attribute__((ext_vector_type(8)));
typedef f16_t f16x4 __attribute__((ext_vector_type(4)));
typedef float floatx4 __attribute__((ext_vector_type(4)));

__device__ __forceinline__ void split2h(float v, f16_t& a, f16_t& b) {
  a = (f16_t)v;
  b = (f16_t)(v - (float)a);
}

// W (rows x K) -> 2 fp16 planes (rows x Kp) row-major, zero-padded K..Kp.
__global__ __launch_bounds__(256) void split_w1h(const float* __restrict__ W,
                                                 f16_t* __restrict__ P,
                                                 long plane, int K, int Kp) {
  int k4 = (blockIdx.x * 256 + threadIdx.x) * 4;
  if (k4 >= Kp) return;
  long r = blockIdx.y;
  float4 v = (k4 < K) ? *(const float4*)(W + r * (long)K + k4)
                      : float4{0.f, 0.f, 0.f, 0.f};
  float t[4] = {v.x, v.y, v.z, v.w};
  f16x4 a, b;
  #pragma unroll
  for (int e = 0; e < 4; ++e) {
    f16_t x, y;
    split2h(t[e], x, y);
    a[e] = x; b[e] = y;
  }
  long o = r * (long)Kp + k4;
  *(f16x4*)(P + o) = a;
  *(f16x4*)(P + plane + o) = b;
}

// GEMM1: 3 fp16 passes (a0b0, a1b0, a0b1); A = x fp32 split in-kernel.
// r2's exact 153-us inner loop; split-K2: blockIdx.y = K-half, atomic out.
// Grid dim3(64, 2, 8): x=mblk (fast), y=kz, z=nblk.
__global__ __launch_bounds__(512, 8) void snn_gemm1(
    const float* __restrict__ Af, long sT, long sB,
    const f16_t* __restrict__ Bp, long planeB, int Kp, int K,
    const float* __restrict__ bias, float* __restrict__ C, int N,
    int tilesPerZ) {
  __shared__ f16_t As[2][128 * LDW];
  __shared__ f16_t Bs[2][128 * LDW];

  const int tid = threadIdx.x;
  const int wave = tid >> 6, lane = tid & 63;
  const int quad = lane >> 4, l16 = lane & 15;
  const int wm = (wave & 3) * 32, wn = (wave >> 2) * 64;
  const long m0 = (long)blockIdx.x * 128, n0 = (long)blockIdx.z * 128;
  const int ktBase = blockIdx.y * tilesPerZ;

  floatx4 acc[2][4];
  #pragma unroll
  for (int i = 0; i < 2; ++i)
    #pragma unroll
    for (int j = 0; j < 4; ++j) acc[i][j] = (floatx4){0.f, 0.f, 0.f, 0.f};

  const int cr = tid >> 2;        // tile row 0..127
  const int cs = (tid & 3) * 8;   // K-seg elem offset 0/8/16/24
  float4 xv[2];
  f16x8 bv[2];
  const float* xrow = Af + ((m0 + cr) >> 8) * sT + ((m0 + cr) & 255) * sB;
  const f16_t* brow = Bp + (n0 + cr) * (long)Kp;

  auto prefetch = [&](int kt) {
    const int k0 = (ktBase + kt) * 32 + cs;
    xv[0] = (k0 < K) ? *(const float4*)(xrow + k0) : float4{0.f, 0.f, 0.f, 0.f};
    xv[1] = (k0 + 4 < K) ? *(const float4*)(xrow + k0 + 4)
                         : float4{0.f, 0.f, 0.f, 0.f};
    #pragma unroll
    for (int q = 0; q < 2; ++q)
      bv[q] = *(const f16x8*)(brow + q * planeB + k0);
  };

  auto commit = [&]() {
    const int off = cr * LDW + cs;
    f16x8 h0, h1;
    float t[8] = {xv[0].x, xv[0].y, xv[0].z, xv[0].w,
                  xv[1].x, xv[1].y, xv[1].z, xv[1].w};
    #pragma unroll
    for (int e = 0; e < 8; ++e) {
      f16_t a, b;
      split2h(t[e], a, b);
      h0[e] = a; h1[e] = b;
    }
    *(f16x8*)(&As[0][off]) = h0;
    *(f16x8*)(&As[1][off]) = h1;
    #pragma unroll
    for (int q = 0; q < 2; ++q) *(f16x8*)(&Bs[q][off]) = bv[q];
  };

  prefetch(0);
  for (int kt = 0; kt < tilesPerZ; ++kt) {
    __syncthreads();   // prior tile's frag reads done
    commit();
    prefetch(kt + 1 < tilesPerZ ? kt + 1 : 0);  // harmless reload at end
    __syncthreads();   // staging visible

    f16x8 afr[2][2];
    #pragma unroll
    for (int pa = 0; pa < 2; ++pa)
      #pragma unroll
      for (int i = 0; i < 2; ++i)
        afr[pa][i] =
            *(const f16x8*)(&As[pa][(wm + i * 16 + l16) * LDW + quad * 8]);

    #pragma unroll
    for (int pb = 0; pb < 2; ++pb) {
      f16x8 bfr[4];
      #pragma unroll
      for (int j = 0; j < 4; ++j)
        bfr[j] =
            *(const f16x8*)(&Bs[pb][(wn + j * 16 + l16) * LDW + quad * 8]);
      const int pamax = 1 - pb;  // passes (0,0),(1,0),(0,1)
      #pragma unroll
      for (int pa = 0; pa < 2; ++pa) {
        if (pa > pamax) break;
        #pragma unroll
        for (int i = 0; i < 2; ++i)
          #pragma unroll
          for (int j = 0; j < 4; ++j)
            acc[i][j] = __builtin_amdgcn_mfma_f32_16x16x32_f16(
                afr[pa][i], bfr[j], acc[i][j], 0, 0, 0);
      }
    }
  }

  // epilogue: C/D layout col=lane&15, row=quad*4+reg (verified).
  // Exactly 2 atomic contributions per element on zeroed C: IEEE-commutative
  // => deterministic. Bias contributed by kz==0 only.
  const bool first = (blockIdx.y == 0);
  #pragma unroll
  for (int j = 0; j < 4; ++j) {
    const long col = n0 + wn + j * 16 + l16;
    const float bvv = first ? bias[col] : 0.f;
    #pragma unroll
    for (int i = 0; i < 2; ++i) {
      const long row0 = m0 + wm + i * 16 + quad * 4;
      #pragma unroll
      for (int g = 0; g < 4; ++g)
        atomicAdd(&C[(row0 + g) * (long)N + col], acc[i][j][g] + bvv);
    }
  }
}

// GEMM2: A = spikes (fp16 exact, 1 plane), B = W2 fp16 2-plane, 2 passes
// (a*b0 + a*b1 = a*(b0+b1): nothing dropped). Same skeleton + split-K2.
__global__ __launch_bounds__(512, 8) void snn_gemm2(
    const f16_t* __restrict__ Ab, long sT, long sB,
    const f16_t* __restrict__ Bp, long planeB, int Kp,
    const float* __restrict__ bias, float* __restrict__ C, int N,
    int tilesPerZ) {
  __shared__ f16_t As[128 * LDW];
  __shared__ f16_t Bs[2][128 * LDW];

  const int tid = threadIdx.x;
  const int wave = tid >> 6, lane = tid & 63;
  const int quad = lane >> 4, l16 = lane & 15;
  const int wm = (wave & 3) * 32, wn = (wave >> 2) * 64;
  const long m0 = (long)blockIdx.x * 128, n0 = (long)blockIdx.z * 128;
  const int ktBase = blockIdx.y * tilesPerZ;

  floatx4 acc[2][4];
  #pragma unroll
  for (int i = 0; i < 2; ++i)
    #pragma unroll
    for (int j = 0; j < 4; ++j) acc[i][j] = (floatx4){0.f, 0.f, 0.f, 0.f};

  const int cr = tid >> 2;
  const int cs = (tid & 3) * 8;
  f16x8 av;
  f16x8 bv[2];
  const f16_t* arow = Ab + ((m0 + cr) >> 8) * sT + ((m0 + cr) & 255) * sB;
  const f16_t* brow = Bp + (n0 + cr) * (long)Kp;

  auto prefetch = [&](int kt) {
    const int k0 = (ktBase + kt) * 32 + cs;
    av = *(const f16x8*)(arow + k0);
    #pragma unroll
    for (int q = 0; q < 2; ++q)
      bv[q] = *(const f16x8*)(brow + q * planeB + k0);
  };

  auto commit = [&]() {
    const int off = cr * LDW + cs;
    *(f16x8*)(&As[off]) = av;
    #pragma unroll
    for (int q = 0; q < 2; ++q) *(f16x8*)(&Bs[q][off]) = bv[q];
  };

  prefetch(0);
  for (int kt = 0; kt < tilesPerZ; ++kt) {
    __syncthreads();
    commit();
    prefetch(kt + 1 < tilesPerZ ? kt + 1 : 0);
    __syncthreads();

    f16x8 afr[2];
    #pragma unroll
    for (int i = 0; i < 2; ++i)
      afr[i] = *(const f16x8*)(&As[(wm + i * 16 + l16) * LDW + quad * 8]);

    #pragma unroll
    for (int pb = 0; pb < 2; ++pb) {
      f16x8 bfr[4];
      #pragma unroll
      for (int j = 0; j < 4; ++j)
        bfr[j] =
            *(const f16x8*)(&Bs[pb][(wn + j * 16 + l16) * LDW + quad * 8]);
      #pragma unroll
      for (int i = 0; i < 2; ++i)
        #pragma unroll
        for (int j = 0; j < 4; ++j)
          acc[i][j] = __builtin_amdgcn_mfma_f32_16x16x32_f16(
              afr[i], bfr[j], acc[i][j], 0, 0, 0);
    }
  }

  const bool first = (blockIdx.y == 0);
  #pragma unroll
  for (int j = 0; j < 4; ++j) {
    const long col = n0 + wn + j * 16 + l16;
    const float bvv = first ? bias[col] : 0.f;
    #pragma unroll
    for (int i = 0; i < 2; ++i) {
      const long row0 = m0 + wm + i * 16 + quad * 4;
      #pragma unroll
      for (int g = 0; g < 4; ++g)
        atomicAdd(&C[(row0 + g) * (long)N + col], acc[i][j][g] + bvv);
    }
  }
}

// LIF scan, fp32 in -> fp16 spikes out (spikes {0,1} exact in fp16).
__global__ __launch_bounds__(256) void lif_scan_f16(const float* __restrict__ I,
                                                    f16_t* __restrict__ S) {
  int idx = blockIdx.x * 256 + threadIdx.x;
  float v = 0.f, cur = 0.f;
  #pragma unroll
  for (int t = 0; t < TT; ++t) {
    float inp = I[(long)t * (TB * TH) + idx];
    float vd = fmaf(0.05f, cur - v, v);
    float id = cur - 0.2f * cur;
    float s = (vd > 1.0f) ? 1.0f : 0.f;
    v = (1.0f - s) * vd;
    cur = id + inp;
    S[(long)t * (TB * TH) + idx] = (f16_t)s;
  }
}

// GEMM3: one wave per row; I3[r][o] = S2[r][:] . Wout[o][:] + bout[o]
__global__ __launch_bounds__(256) void gemm3_kernel(
    const f16_t* __restrict__ S2, const float* __restrict__ Wout,
    const float* __restrict__ bout, float* __restrict__ I3) {
  int wv = (blockIdx.x * blockDim.x + threadIdx.x) >> 6;
  int lane = threadIdx.x & 63;
  if (wv >= TM) return;
  const f16_t* srow = S2 + (long)wv * TH;
  float acc[TOUT];
  #pragma unroll
  for (int o = 0; o < TOUT; ++o) acc[o] = 0.f;
  for (int k = lane; k < TH; k += 64) {
    float s = (float)srow[k];
    #pragma unroll
    for (int o = 0; o < TOUT; ++o) acc[o] = fmaf(s, Wout[o * TH + k], acc[o]);
  }
  #pragma unroll
  for (int off = 32; off > 0; off >>= 1)
    #pragma unroll
    for (int o = 0; o < TOUT; ++o) acc[o] += __shfl_down(acc[o], off, 64);
  if (lane == 0) {
    #pragma unroll
    for (int o = 0; o < TOUT; ++o) I3[(long)wv * TOUT + o] = acc[o] + bout[o];
  }
}

__global__ __launch_bounds__(256) void scan_out(const float* __restrict__ I3,
                                                float* __restrict__ out) {
  int idx = blockIdx.x * blockDim.x + threadIdx.x;
  if (idx >= TB * TOUT) return;
  float v = 0.f, cur = 0.f, cnt = 0.f;
  #pragma unroll
  for (int t = 0; t < TT; ++t) {
    float inp = I3[(long)t * (TB * TOUT) + idx];
    float vd = fmaf(0.05f, cur - v, v);
    float id = cur - 0.2f * cur;
    float s = (vd > 1.0f) ? 1.0f : 0.f;
    v = (1.0f - s) * vd;
    cur = id + inp;
    cnt += s;
  }
  out[idx] = cnt;
}

extern "C" void kernel_launch(void* const* d_in, const int* in_sizes, int n_in,
                              void* d_out, int out_size, void* d_ws,
                              size_t ws_size, hipStream_t stream) {
  const float* x    = (const float*)d_in[0];  // (256,32,2312)
  const float* W1   = (const float*)d_in[1];  // (1024,2312)
  const float* b1   = (const float*)d_in[2];
  const float* W2   = (const float*)d_in[3];  // (1024,1024)
  const float* b2   = (const float*)d_in[4];
  const float* Wout = (const float*)d_in[5];  // (10,1024)
  const float* bout = (const float*)d_in[6];

  // ws layout (bytes), identical to round-3's verified layout:
  //   [0, 16.78M)      : W1p (fp16 2-plane, 9.70M) + W2p (fp16 2-plane,
  //                      4.19M) -- dead after GEMM2; S2 (fp16, 16.78M)
  //                      ALIASES this region (stream-sequential safe).
  //   [16.78M, 50.33M) : bufI (fp32, 33.55M)
  //   [50.33M, 67.11M) : S1 (fp16, 16.78M)
  //   [67.11M, 67.44M) : buf3 (fp32, 0.33M)
  char* base = (char*)d_ws;
  const long S2_BYTES = (long)TM * TH * 2;  // 16,777,216
  f16_t* W1p  = (f16_t*)base;
  f16_t* W2p  = (f16_t*)(base + 2L * TH * KP1 * 2);  // after 9,699,328 B
  float* bufI = (float*)(base + S2_BYTES);
  f16_t* S1   = (f16_t*)(base + S2_BYTES + (long)TM * TH * 4);
  float* buf3 = (float*)(base + S2_BYTES + (long)TM * TH * 4 + (long)TM * TH * 2);
  f16_t* S2   = (f16_t*)base;

  split_w1h<<<dim3(3, TH), 256, 0, stream>>>(W1, W1p, (long)TH * KP1, TIN, KP1);
  split_w1h<<<dim3(1, TH), 256, 0, stream>>>(W2, W2p, (long)TH * TH, TH, TH);

  // GEMM1: row r=(t,b): x offset = t*2312 + b*(32*2312). Split-K2 atomic.
  hipMemsetAsync(bufI, 0, (long)TM * TH * 4, stream);
  snn_gemm1<<<dim3(64, 2, 8), 512, 0, stream>>>(
      x, (long)TIN, (long)TT * TIN, W1p, (long)TH * KP1, KP1, TIN, b1, bufI,
      TH, 37);

  lif_scan_f16<<<(TB * TH) / 256, 256, 0, stream>>>(bufI, S1);

  // GEMM2: S1 row-major [8192][1024]: sT=256*1024, sB=1024. Split-K2 atomic.
  hipMemsetAsync(bufI, 0, (long)TM * TH * 4, stream);
  snn_gemm2<<<dim3(64, 2, 8), 512, 0, stream>>>(
      S1, (long)TB * TH, (long)TH, W2p, (long)TH * TH, TH, b2, bufI, TH, 16);

  lif_scan_f16<<<(TB * TH) / 256, 256, 0, stream>>>(bufI, S2);

  gemm3_kernel<<<(TM * 64) / 256, 256, 0, stream>>>(S2, Wout, bout, buf3);

  scan_out<<<(TB * TOUT + 255) / 256, 256, 0, stream>>>(buf3, (float*)d_out);
}

// Round 9
// 395.603 us; speedup vs baseline: 2.8790x; 2.8790x over previous
//
#include <hip/hip_runtime.h>

// SNN: 3-layer LIF, B=256, T=32, H=1024, IN=2312, OUT=10.
// r2 G1 (fp16 2-plane 3-pass, 128^2, 512thr, LDW=36) = 153us @ 2 blk/CU,
//   VGPR 52 under launch_bounds(512,4) -- grid (512 blocks) was the only
//   thing capping residency at 2 blk/CU.
// r8: split-K2 (grid 1024 = 4 blk/CU) PROVEN to raise occupancy to 79% and
//   absmax 0.0 PROVEN for the atomic combine -- but launch_bounds(512,8)
//   forced VGPR 32 -> total spill (FETCH 1.7GB, 842us).
// Round-12: r8 with the r2 bound: launch_bounds(512,4). Compiler lands
//   ~52-60 VGPR naturally (<=64) -> HW schedules 8 waves/SIMD -> 4 blk/CU,
//   32 waves/CU, no spill. K-halves combine by atomicAdd onto memset-zeroed
//   bufI: exactly 2 IEEE-commutative adds per output => deterministic.
//   Bias added by the kz==0 contribution only. Grid dim3(64,2,8):
//   mblk fastest, kz inside nblk => each XCD chunk (128 blocks) covers both
//   K-halves of ONE nblk -> B slice 2.42MB stays XCD-L2-pinned (r6-proven).

#define TB 256
#define TT 32
#define TH 1024
#define TIN 2312
#define TOUT 10
#define TM (TT * TB)   // 8192 rows = (t,b)
#define KP1 2368       // TIN padded to multiple of 32 (74 tiles; 37/z)
#define LDW 36         // 32 + 4 pad (r2-verified: frag reads ~2-way, free)

typedef _Float16 f16_t;
typedef f16_t f16x8 __attribute__((ext_vector_type(8)));
typedef f16_t f16x4 __attribute__((ext_vector_type(4)));
typedef float floatx4 __attribute__((ext_vector_type(4)));

__device__ __forceinline__ void split2h(float v, f16_t& a, f16_t& b) {
  a = (f16_t)v;
  b = (f16_t)(v - (float)a);
}

// W (rows x K) -> 2 fp16 planes (rows x Kp) row-major, zero-padded K..Kp.
__global__ __launch_bounds__(256) void split_w1h(const float* __restrict__ W,
                                                 f16_t* __restrict__ P,
                                                 long plane, int K, int Kp) {
  int k4 = (blockIdx.x * 256 + threadIdx.x) * 4;
  if (k4 >= Kp) return;
  long r = blockIdx.y;
  float4 v = (k4 < K) ? *(const float4*)(W + r * (long)K + k4)
                      : float4{0.f, 0.f, 0.f, 0.f};
  float t[4] = {v.x, v.y, v.z, v.w};
  f16x4 a, b;
  #pragma unroll
  for (int e = 0; e < 4; ++e) {
    f16_t x, y;
    split2h(t[e], x, y);
    a[e] = x; b[e] = y;
  }
  long o = r * (long)Kp + k4;
  *(f16x4*)(P + o) = a;
  *(f16x4*)(P + plane + o) = b;
}

// GEMM1: 3 fp16 passes (a0b0, a1b0, a0b1); A = x fp32 split in-kernel.
// r2's exact inner loop; split-K2: blockIdx.y = K-half, atomic out.
// Grid dim3(64, 2, 8): x=mblk (fast), y=kz, z=nblk.
__global__ __launch_bounds__(512, 4) void snn_gemm1(
    const float* __restrict__ Af, long sT, long sB,
    const f16_t* __restrict__ Bp, long planeB, int Kp, int K,
    const float* __restrict__ bias, float* __restrict__ C, int N,
    int tilesPerZ) {
  __shared__ f16_t As[2][128 * LDW];
  __shared__ f16_t Bs[2][128 * LDW];

  const int tid = threadIdx.x;
  const int wave = tid >> 6, lane = tid & 63;
  const int quad = lane >> 4, l16 = lane & 15;
  const int wm = (wave & 3) * 32, wn = (wave >> 2) * 64;
  const long m0 = (long)blockIdx.x * 128, n0 = (long)blockIdx.z * 128;
  const int ktBase = blockIdx.y * tilesPerZ;

  floatx4 acc[2][4];
  #pragma unroll
  for (int i = 0; i < 2; ++i)
    #pragma unroll
    for (int j = 0; j < 4; ++j) acc[i][j] = (floatx4){0.f, 0.f, 0.f, 0.f};

  const int cr = tid >> 2;        // tile row 0..127
  const int cs = (tid & 3) * 8;   // K-seg elem offset 0/8/16/24
  float4 xv[2];
  f16x8 bv[2];
  const float* xrow = Af + ((m0 + cr) >> 8) * sT + ((m0 + cr) & 255) * sB;
  const f16_t* brow = Bp + (n0 + cr) * (long)Kp;

  auto prefetch = [&](int kt) {
    const int k0 = (ktBase + kt) * 32 + cs;
    xv[0] = (k0 < K) ? *(const float4*)(xrow + k0) : float4{0.f, 0.f, 0.f, 0.f};
    xv[1] = (k0 + 4 < K) ? *(const float4*)(xrow + k0 + 4)
                         : float4{0.f, 0.f, 0.f, 0.f};
    #pragma unroll
    for (int q = 0; q < 2; ++q)
      bv[q] = *(const f16x8*)(brow + q * planeB + k0);
  };

  auto commit = [&]() {
    const int off = cr * LDW + cs;
    f16x8 h0, h1;
    float t[8] = {xv[0].x, xv[0].y, xv[0].z, xv[0].w,
                  xv[1].x, xv[1].y, xv[1].z, xv[1].w};
    #pragma unroll
    for (int e = 0; e < 8; ++e) {
      f16_t a, b;
      split2h(t[e], a, b);
      h0[e] = a; h1[e] = b;
    }
    *(f16x8*)(&As[0][off]) = h0;
    *(f16x8*)(&As[1][off]) = h1;
    #pragma unroll
    for (int q = 0; q < 2; ++q) *(f16x8*)(&Bs[q][off]) = bv[q];
  };

  prefetch(0);
  for (int kt = 0; kt < tilesPerZ; ++kt) {
    __syncthreads();   // prior tile's frag reads done
    commit();
    prefetch(kt + 1 < tilesPerZ ? kt + 1 : 0);  // harmless reload at end
    __syncthreads();   // staging visible

    f16x8 afr[2][2];
    #pragma unroll
    for (int pa = 0; pa < 2; ++pa)
      #pragma unroll
      for (int i = 0; i < 2; ++i)
        afr[pa][i] =
            *(const f16x8*)(&As[pa][(wm + i * 16 + l16) * LDW + quad * 8]);

    #pragma unroll
    for (int pb = 0; pb < 2; ++pb) {
      f16x8 bfr[4];
      #pragma unroll
      for (int j = 0; j < 4; ++j)
        bfr[j] =
            *(const f16x8*)(&Bs[pb][(wn + j * 16 + l16) * LDW + quad * 8]);
      const int pamax = 1 - pb;  // passes (0,0),(1,0),(0,1)
      #pragma unroll
      for (int pa = 0; pa < 2; ++pa) {
        if (pa > pamax) break;
        #pragma unroll
        for (int i = 0; i < 2; ++i)
          #pragma unroll
          for (int j = 0; j < 4; ++j)
            acc[i][j] = __builtin_amdgcn_mfma_f32_16x16x32_f16(
                afr[pa][i], bfr[j], acc[i][j], 0, 0, 0);
      }
    }
  }

  // epilogue: C/D layout col=lane&15, row=quad*4+reg (verified).
  // Exactly 2 atomic contributions per element on zeroed C: IEEE-commutative
  // => deterministic. Bias contributed by kz==0 only.
  const bool first = (blockIdx.y == 0);
  #pragma unroll
  for (int j = 0; j < 4; ++j) {
    const long col = n0 + wn + j * 16 + l16;
    const float bvv = first ? bias[col] : 0.f;
    #pragma unroll
    for (int i = 0; i < 2; ++i) {
      const long row0 = m0 + wm + i * 16 + quad * 4;
      #pragma unroll
      for (int g = 0; g < 4; ++g)
        atomicAdd(&C[(row0 + g) * (long)N + col], acc[i][j][g] + bvv);
    }
  }
}

// GEMM2: A = spikes (fp16 exact, 1 plane), B = W2 fp16 2-plane, 2 passes
// (a*b0 + a*b1 = a*(b0+b1): nothing dropped). Same skeleton + split-K2.
__global__ __launch_bounds__(512, 4) void snn_gemm2(
    const f16_t* __restrict__ Ab, long sT, long sB,
    const f16_t* __restrict__ Bp, long planeB, int Kp,
    const float* __restrict__ bias, float* __restrict__ C, int N,
    int tilesPerZ) {
  __shared__ f16_t As[128 * LDW];
  __shared__ f16_t Bs[2][128 * LDW];

  const int tid = threadIdx.x;
  const int wave = tid >> 6, lane = tid & 63;
  const int quad = lane >> 4, l16 = lane & 15;
  const int wm = (wave & 3) * 32, wn = (wave >> 2) * 64;
  const long m0 = (long)blockIdx.x * 128, n0 = (long)blockIdx.z * 128;
  const int ktBase = blockIdx.y * tilesPerZ;

  floatx4 acc[2][4];
  #pragma unroll
  for (int i = 0; i < 2; ++i)
    #pragma unroll
    for (int j = 0; j < 4; ++j) acc[i][j] = (floatx4){0.f, 0.f, 0.f, 0.f};

  const int cr = tid >> 2;
  const int cs = (tid & 3) * 8;
  f16x8 av;
  f16x8 bv[2];
  const f16_t* arow = Ab + ((m0 + cr) >> 8) * sT + ((m0 + cr) & 255) * sB;
  const f16_t* brow = Bp + (n0 + cr) * (long)Kp;

  auto prefetch = [&](int kt) {
    const int k0 = (ktBase + kt) * 32 + cs;
    av = *(const f16x8*)(arow + k0);
    #pragma unroll
    for (int q = 0; q < 2; ++q)
      bv[q] = *(const f16x8*)(brow + q * planeB + k0);
  };

  auto commit = [&]() {
    const int off = cr * LDW + cs;
    *(f16x8*)(&As[off]) = av;
    #pragma unroll
    for (int q = 0; q < 2; ++q) *(f16x8*)(&Bs[q][off]) = bv[q];
  };

  prefetch(0);
  for (int kt = 0; kt < tilesPerZ; ++kt) {
    __syncthreads();
    commit();
    prefetch(kt + 1 < tilesPerZ ? kt + 1 : 0);
    __syncthreads();

    f16x8 afr[2];
    #pragma unroll
    for (int i = 0; i < 2; ++i)
      afr[i] = *(const f16x8*)(&As[(wm + i * 16 + l16) * LDW + quad * 8]);

    #pragma unroll
    for (int pb = 0; pb < 2; ++pb) {
      f16x8 bfr[4];
      #pragma unroll
      for (int j = 0; j < 4; ++j)
        bfr[j] =
            *(const f16x8*)(&Bs[pb][(wn + j * 16 + l16) * LDW + quad * 8]);
      #pragma unroll
      for (int i = 0; i < 2; ++i)
        #pragma unroll
        for (int j = 0; j < 4; ++j)
          acc[i][j] = __builtin_amdgcn_mfma_f32_16x16x32_f16(
              afr[i], bfr[j], acc[i][j], 0, 0, 0);
    }
  }

  const bool first = (blockIdx.y == 0);
  #pragma unroll
  for (int j = 0; j < 4; ++j) {
    const long col = n0 + wn + j * 16 + l16;
    const float bvv = first ? bias[col] : 0.f;
    #pragma unroll
    for (int i = 0; i < 2; ++i) {
      const long row0 = m0 + wm + i * 16 + quad * 4;
      #pragma unroll
      for (int g = 0; g < 4; ++g)
        atomicAdd(&C[(row0 + g) * (long)N + col], acc[i][j][g] + bvv);
    }
  }
}

// LIF scan, fp32 in -> fp16 spikes out (spikes {0,1} exact in fp16).
__global__ __launch_bounds__(256) void lif_scan_f16(const float* __restrict__ I,
                                                    f16_t* __restrict__ S) {
  int idx = blockIdx.x * 256 + threadIdx.x;
  float v = 0.f, cur = 0.f;
  #pragma unroll
  for (int t = 0; t < TT; ++t) {
    float inp = I[(long)t * (TB * TH) + idx];
    float vd = fmaf(0.05f, cur - v, v);
    float id = cur - 0.2f * cur;
    float s = (vd > 1.0f) ? 1.0f : 0.f;
    v = (1.0f - s) * vd;
    cur = id + inp;
    S[(long)t * (TB * TH) + idx] = (f16_t)s;
  }
}

// GEMM3: one wave per row; I3[r][o] = S2[r][:] . Wout[o][:] + bout[o]
__global__ __launch_bounds__(256) void gemm3_kernel(
    const f16_t* __restrict__ S2, const float* __restrict__ Wout,
    const float* __restrict__ bout, float* __restrict__ I3) {
  int wv = (blockIdx.x * blockDim.x + threadIdx.x) >> 6;
  int lane = threadIdx.x & 63;
  if (wv >= TM) return;
  const f16_t* srow = S2 + (long)wv * TH;
  float acc[TOUT];
  #pragma unroll
  for (int o = 0; o < TOUT; ++o) acc[o] = 0.f;
  for (int k = lane; k < TH; k += 64) {
    float s = (float)srow[k];
    #pragma unroll
    for (int o = 0; o < TOUT; ++o) acc[o] = fmaf(s, Wout[o * TH + k], acc[o]);
  }
  #pragma unroll
  for (int off = 32; off > 0; off >>= 1)
    #pragma unroll
    for (int o = 0; o < TOUT; ++o) acc[o] += __shfl_down(acc[o], off, 64);
  if (lane == 0) {
    #pragma unroll
    for (int o = 0; o < TOUT; ++o) I3[(long)wv * TOUT + o] = acc[o] + bout[o];
  }
}

__global__ __launch_bounds__(256) void scan_out(const float* __restrict__ I3,
                                                float* __restrict__ out) {
  int idx = blockIdx.x * blockDim.x + threadIdx.x;
  if (idx >= TB * TOUT) return;
  float v = 0.f, cur = 0.f, cnt = 0.f;
  #pragma unroll
  for (int t = 0; t < TT; ++t) {
    float inp = I3[(long)t * (TB * TOUT) + idx];
    float vd = fmaf(0.05f, cur - v, v);
    float id = cur - 0.2f * cur;
    float s = (vd > 1.0f) ? 1.0f : 0.f;
    v = (1.0f - s) * vd;
    cur = id + inp;
    cnt += s;
  }
  out[idx] = cnt;
}

extern "C" void kernel_launch(void* const* d_in, const int* in_sizes, int n_in,
                              void* d_out, int out_size, void* d_ws,
                              size_t ws_size, hipStream_t stream) {
  const float* x    = (const float*)d_in[0];  // (256,32,2312)
  const float* W1   = (const float*)d_in[1];  // (1024,2312)
  const float* b1   = (const float*)d_in[2];
  const float* W2   = (const float*)d_in[3];  // (1024,1024)
  const float* b2   = (const float*)d_in[4];
  const float* Wout = (const float*)d_in[5];  // (10,1024)
  const float* bout = (const float*)d_in[6];

  // ws layout (bytes), identical to round-3's verified layout:
  //   [0, 16.78M)      : W1p (fp16 2-plane, 9.70M) + W2p (fp16 2-plane,
  //                      4.19M) -- dead after GEMM2; S2 (fp16, 16.78M)
  //                      ALIASES this region (stream-sequential safe).
  //   [16.78M, 50.33M) : bufI (fp32, 33.55M)
  //   [50.33M, 67.11M) : S1 (fp16, 16.78M)
  //   [67.11M, 67.44M) : buf3 (fp32, 0.33M)
  char* base = (char*)d_ws;
  const long S2_BYTES = (long)TM * TH * 2;  // 16,777,216
  f16_t* W1p  = (f16_t*)base;
  f16_t* W2p  = (f16_t*)(base + 2L * TH * KP1 * 2);  // after 9,699,328 B
  float* bufI = (float*)(base + S2_BYTES);
  f16_t* S1   = (f16_t*)(base + S2_BYTES + (long)TM * TH * 4);
  float* buf3 = (float*)(base + S2_BYTES + (long)TM * TH * 4 + (long)TM * TH * 2);
  f16_t* S2   = (f16_t*)base;

  split_w1h<<<dim3(3, TH), 256, 0, stream>>>(W1, W1p, (long)TH * KP1, TIN, KP1);
  split_w1h<<<dim3(1, TH), 256, 0, stream>>>(W2, W2p, (long)TH * TH, TH, TH);

  // GEMM1: row r=(t,b): x offset = t*2312 + b*(32*2312). Split-K2 atomic.
  hipMemsetAsync(bufI, 0, (long)TM * TH * 4, stream);
  snn_gemm1<<<dim3(64, 2, 8), 512, 0, stream>>>(
      x, (long)TIN, (long)TT * TIN, W1p, (long)TH * KP1, KP1, TIN, b1, bufI,
      TH, 37);

  lif_scan_f16<<<(TB * TH) / 256, 256, 0, stream>>>(bufI, S1);

  // GEMM2: S1 row-major [8192][1024]: sT=256*1024, sB=1024. Split-K2 atomic.
  hipMemsetAsync(bufI, 0, (long)TM * TH * 4, stream);
  snn_gemm2<<<dim3(64, 2, 8), 512, 0, stream>>>(
      S1, (long)TB * TH, (long)TH, W2p, (long)TH * TH, TH, b2, bufI, TH, 16);

  lif_scan_f16<<<(TB * TH) / 256, 256, 0, stream>>>(bufI, S2);

  gemm3_kernel<<<(TM * 64) / 256, 256, 0, stream>>>(S2, Wout, bout, buf3);

  scan_out<<<(TB * TOUT + 255) / 256, 256, 0, stream>>>(buf3, (float*)d_out);
}

// Round 10
// 322.035 us; speedup vs baseline: 3.5367x; 1.2284x over previous
//
#include <hip/hip_runtime.h>

// SNN: 3-layer LIF, B=256, T=32, H=1024, IN=2312, OUT=10.
// Session ledger: r2's G1 (fp16 2-plane 3-pass, 128^2, 512thr 4Mx2N waves,
//   LDW=36, grid (64,8) mblk-fast, lb(512,4)) = 153.9us -- best of 9
//   structural variants (frag-LDS, B-direct, 256-tile 4-phase, split-K2 all
//   slower; split-K2 r9: occupancy did NOT rise (38%), atomics +130MB HBM).
// Round-13: recombine best-known pieces, no new structure:
//   G1 = byte-faithful r2 kernel. G2 = same skeleton, fp16 2-plane 2-pass
//   (spikes exact in fp16; a*b0 + a*b1 = a*(b0+b1), nothing dropped) --
//   replaces the bf16 3-plane 3-pass G2 that ran in the 334.9us r2 bench.
//   Expected G2 ~48us vs ~70us. No memset/atomic/split-K.

#define TB 256
#define TT 32
#define TH 1024
#define TIN 2312
#define TOUT 10
#define TM (TT * TB)   // 8192 rows = (t,b)
#define KP1 2368       // TIN padded to multiple of 32
#define LDW 36         // 32 + 4 pad (r2-verified: frag reads ~2-way, free)

typedef _Float16 f16_t;
typedef f16_t f16x8 __attribute__((ext_vector_type(8)));
typedef f16_t f16x4 __attribute__((ext_vector_type(4)));
typedef float floatx4 __attribute__((ext_vector_type(4)));

__device__ __forceinline__ void split2h(float v, f16_t& a, f16_t& b) {
  a = (f16_t)v;
  b = (f16_t)(v - (float)a);
}

// W (rows x K) -> 2 fp16 planes (rows x Kp) row-major, zero-padded K..Kp.
__global__ __launch_bounds__(256) void split_w1h(const float* __restrict__ W,
                                                 f16_t* __restrict__ P,
                                                 long plane, int K, int Kp) {
  int k4 = (blockIdx.x * 256 + threadIdx.x) * 4;
  if (k4 >= Kp) return;
  long r = blockIdx.y;
  float4 v = (k4 < K) ? *(const float4*)(W + r * (long)K + k4)
                      : float4{0.f, 0.f, 0.f, 0.f};
  float t[4] = {v.x, v.y, v.z, v.w};
  f16x4 a, b;
  #pragma unroll
  for (int e = 0; e < 4; ++e) {
    f16_t x, y;
    split2h(t[e], x, y);
    a[e] = x; b[e] = y;
  }
  long o = r * (long)Kp + k4;
  *(f16x4*)(P + o) = a;
  *(f16x4*)(P + plane + o) = b;
}

// GEMM1: C[r][n] = 3 fp16 passes of A(x fp32, split in-kernel) x
// B(W1 fp16 2-plane) + bias. A row elem offset = (r>>8)*sT + (r&255)*sB.
// 512 threads = 8 waves 4(M)x2(N); per-wave 32x64.  [r2: 153.9us verified]
__global__ __launch_bounds__(512, 4) void snn_gemm1(
    const float* __restrict__ Af, long sT, long sB,
    const f16_t* __restrict__ Bp, long planeB, int Kp, int K,
    const float* __restrict__ bias, float* __restrict__ C, int N) {
  __shared__ f16_t As[2][128 * LDW];
  __shared__ f16_t Bs[2][128 * LDW];

  const int tid = threadIdx.x;
  const int wave = tid >> 6, lane = tid & 63;
  const int quad = lane >> 4, l16 = lane & 15;
  const int wm = (wave & 3) * 32, wn = (wave >> 2) * 64;
  const long m0 = (long)blockIdx.x * 128, n0 = (long)blockIdx.y * 128;

  floatx4 acc[2][4];
  #pragma unroll
  for (int i = 0; i < 2; ++i)
    #pragma unroll
    for (int j = 0; j < 4; ++j) acc[i][j] = (floatx4){0.f, 0.f, 0.f, 0.f};

  const int cr = tid >> 2;        // tile row 0..127
  const int cs = (tid & 3) * 8;   // K-seg elem offset 0/8/16/24
  float4 xv[2];
  f16x8 bv[2];

  auto prefetch = [&](int kb) {
    const long rA = m0 + cr;
    const int k0 = kb + cs;
    const float* xr = Af + (rA >> 8) * sT + (rA & 255) * sB + k0;
    xv[0] = (k0 < K) ? *(const float4*)xr : float4{0.f, 0.f, 0.f, 0.f};
    xv[1] = (k0 + 4 < K) ? *(const float4*)(xr + 4)
                         : float4{0.f, 0.f, 0.f, 0.f};
    #pragma unroll
    for (int q = 0; q < 2; ++q)
      bv[q] = *(const f16x8*)(Bp + q * planeB + (n0 + cr) * (long)Kp + k0);
  };

  auto commit = [&]() {
    const int off = cr * LDW + cs;
    f16x8 h0, h1;
    float t[8] = {xv[0].x, xv[0].y, xv[0].z, xv[0].w,
                  xv[1].x, xv[1].y, xv[1].z, xv[1].w};
    #pragma unroll
    for (int e = 0; e < 8; ++e) {
      f16_t a, b;
      split2h(t[e], a, b);
      h0[e] = a; h1[e] = b;
    }
    *(f16x8*)(&As[0][off]) = h0;
    *(f16x8*)(&As[1][off]) = h1;
    #pragma unroll
    for (int q = 0; q < 2; ++q) *(f16x8*)(&Bs[q][off]) = bv[q];
  };

  const int numT = Kp / 32;
  prefetch(0);
  for (int kt = 0; kt < numT; ++kt) {
    __syncthreads();   // prior tile's frag reads done
    commit();
    const int kbn = (kt + 1 < numT) ? (kt + 1) * 32 : 0;  // harmless reload
    prefetch(kbn);     // next tile: global latency hides behind MFMA phase
    __syncthreads();   // staging visible

    f16x8 afr[2][2];
    #pragma unroll
    for (int pa = 0; pa < 2; ++pa)
      #pragma unroll
      for (int i = 0; i < 2; ++i)
        afr[pa][i] =
            *(const f16x8*)(&As[pa][(wm + i * 16 + l16) * LDW + quad * 8]);

    #pragma unroll
    for (int pb = 0; pb < 2; ++pb) {
      f16x8 bfr[4];
      #pragma unroll
      for (int j = 0; j < 4; ++j)
        bfr[j] =
            *(const f16x8*)(&Bs[pb][(wn + j * 16 + l16) * LDW + quad * 8]);
      const int pamax = 1 - pb;  // passes (0,0),(1,0),(0,1)
      #pragma unroll
      for (int pa = 0; pa < 2; ++pa) {
        if (pa > pamax) break;
        #pragma unroll
        for (int i = 0; i < 2; ++i)
          #pragma unroll
          for (int j = 0; j < 4; ++j)
            acc[i][j] = __builtin_amdgcn_mfma_f32_16x16x32_f16(
                afr[pa][i], bfr[j], acc[i][j], 0, 0, 0);
      }
    }
  }

  // epilogue: C/D layout col=lane&15, row=quad*4+reg (m89/m91-verified)
  #pragma unroll
  for (int j = 0; j < 4; ++j) {
    const long col = n0 + wn + j * 16 + l16;
    const float bvv = bias[col];
    #pragma unroll
    for (int i = 0; i < 2; ++i) {
      const long row0 = m0 + wm + i * 16 + quad * 4;
      #pragma unroll
      for (int g = 0; g < 4; ++g)
        C[(row0 + g) * (long)N + col] = acc[i][j][g] + bvv;
    }
  }
}

// GEMM2: A = spikes (fp16 exact, 1 plane), B = W2 fp16 2-plane, 2 passes
// (a*b0 + a*b1 = a*(b0+b1): nothing dropped). Same r2 skeleton.
__global__ __launch_bounds__(512, 4) void snn_gemm2(
    const f16_t* __restrict__ Ab, long sT, long sB,
    const f16_t* __restrict__ Bp, long planeB, int Kp,
    const float* __restrict__ bias, float* __restrict__ C, int N) {
  __shared__ f16_t As[128 * LDW];
  __shared__ f16_t Bs[2][128 * LDW];

  const int tid = threadIdx.x;
  const int wave = tid >> 6, lane = tid & 63;
  const int quad = lane >> 4, l16 = lane & 15;
  const int wm = (wave & 3) * 32, wn = (wave >> 2) * 64;
  const long m0 = (long)blockIdx.x * 128, n0 = (long)blockIdx.y * 128;

  floatx4 acc[2][4];
  #pragma unroll
  for (int i = 0; i < 2; ++i)
    #pragma unroll
    for (int j = 0; j < 4; ++j) acc[i][j] = (floatx4){0.f, 0.f, 0.f, 0.f};

  const int cr = tid >> 2;
  const int cs = (tid & 3) * 8;
  f16x8 av;
  f16x8 bv[2];

  auto prefetch = [&](int kb) {
    const long rA = m0 + cr;
    av = *(const f16x8*)(Ab + (rA >> 8) * sT + (rA & 255) * sB + kb + cs);
    #pragma unroll
    for (int q = 0; q < 2; ++q)
      bv[q] = *(const f16x8*)(Bp + q * planeB + (n0 + cr) * (long)Kp + kb + cs);
  };

  auto commit = [&]() {
    const int off = cr * LDW + cs;
    *(f16x8*)(&As[off]) = av;
    #pragma unroll
    for (int q = 0; q < 2; ++q) *(f16x8*)(&Bs[q][off]) = bv[q];
  };

  const int numT = Kp / 32;
  prefetch(0);
  for (int kt = 0; kt < numT; ++kt) {
    __syncthreads();
    commit();
    const int kbn = (kt + 1 < numT) ? (kt + 1) * 32 : 0;
    prefetch(kbn);
    __syncthreads();

    f16x8 afr[2];
    #pragma unroll
    for (int i = 0; i < 2; ++i)
      afr[i] = *(const f16x8*)(&As[(wm + i * 16 + l16) * LDW + quad * 8]);

    #pragma unroll
    for (int pb = 0; pb < 2; ++pb) {
      f16x8 bfr[4];
      #pragma unroll
      for (int j = 0; j < 4; ++j)
        bfr[j] =
            *(const f16x8*)(&Bs[pb][(wn + j * 16 + l16) * LDW + quad * 8]);
      #pragma unroll
      for (int i = 0; i < 2; ++i)
        #pragma unroll
        for (int j = 0; j < 4; ++j)
          acc[i][j] = __builtin_amdgcn_mfma_f32_16x16x32_f16(
              afr[i], bfr[j], acc[i][j], 0, 0, 0);
    }
  }

  #pragma unroll
  for (int j = 0; j < 4; ++j) {
    const long col = n0 + wn + j * 16 + l16;
    const float bvv = bias[col];
    #pragma unroll
    for (int i = 0; i < 2; ++i) {
      const long row0 = m0 + wm + i * 16 + quad * 4;
      #pragma unroll
      for (int g = 0; g < 4; ++g)
        C[(row0 + g) * (long)N + col] = acc[i][j][g] + bvv;
    }
  }
}

// LIF scan, fp32 in -> fp16 spikes out (spikes {0,1} exact in fp16).
__global__ __launch_bounds__(256) void lif_scan_f16(const float* __restrict__ I,
                                                    f16_t* __restrict__ S) {
  int idx = blockIdx.x * 256 + threadIdx.x;
  float v = 0.f, cur = 0.f;
  #pragma unroll
  for (int t = 0; t < TT; ++t) {
    float inp = I[(long)t * (TB * TH) + idx];
    float vd = fmaf(0.05f, cur - v, v);
    float id = cur - 0.2f * cur;
    float s = (vd > 1.0f) ? 1.0f : 0.f;
    v = (1.0f - s) * vd;
    cur = id + inp;
    S[(long)t * (TB * TH) + idx] = (f16_t)s;
  }
}

// GEMM3: one wave per row; I3[r][o] = S2[r][:] . Wout[o][:] + bout[o]
__global__ __launch_bounds__(256) void gemm3_kernel(
    const f16_t* __restrict__ S2, const float* __restrict__ Wout,
    const float* __restrict__ bout, float* __restrict__ I3) {
  int wv = (blockIdx.x * blockDim.x + threadIdx.x) >> 6;
  int lane = threadIdx.x & 63;
  if (wv >= TM) return;
  const f16_t* srow = S2 + (long)wv * TH;
  float acc[TOUT];
  #pragma unroll
  for (int o = 0; o < TOUT; ++o) acc[o] = 0.f;
  for (int k = lane; k < TH; k += 64) {
    float s = (float)srow[k];
    #pragma unroll
    for (int o = 0; o < TOUT; ++o) acc[o] = fmaf(s, Wout[o * TH + k], acc[o]);
  }
  #pragma unroll
  for (int off = 32; off > 0; off >>= 1)
    #pragma unroll
    for (int o = 0; o < TOUT; ++o) acc[o] += __shfl_down(acc[o], off, 64);
  if (lane == 0) {
    #pragma unroll
    for (int o = 0; o < TOUT; ++o) I3[(long)wv * TOUT + o] = acc[o] + bout[o];
  }
}

__global__ __launch_bounds__(256) void scan_out(const float* __restrict__ I3,
                                                float* __restrict__ out) {
  int idx = blockIdx.x * blockDim.x + threadIdx.x;
  if (idx >= TB * TOUT) return;
  float v = 0.f, cur = 0.f, cnt = 0.f;
  #pragma unroll
  for (int t = 0; t < TT; ++t) {
    float inp = I3[(long)t * (TB * TOUT) + idx];
    float vd = fmaf(0.05f, cur - v, v);
    float id = cur - 0.2f * cur;
    float s = (vd > 1.0f) ? 1.0f : 0.f;
    v = (1.0f - s) * vd;
    cur = id + inp;
    cnt += s;
  }
  out[idx] = cnt;
}

extern "C" void kernel_launch(void* const* d_in, const int* in_sizes, int n_in,
                              void* d_out, int out_size, void* d_ws,
                              size_t ws_size, hipStream_t stream) {
  const float* x    = (const float*)d_in[0];  // (256,32,2312)
  const float* W1   = (const float*)d_in[1];  // (1024,2312)
  const float* b1   = (const float*)d_in[2];
  const float* W2   = (const float*)d_in[3];  // (1024,1024)
  const float* b2   = (const float*)d_in[4];
  const float* Wout = (const float*)d_in[5];  // (10,1024)
  const float* bout = (const float*)d_in[6];

  // ws layout (bytes), round-3-verified:
  //   [0, 16.78M)      : W1p (fp16 2-plane, 9.70M) + W2p (fp16 2-plane,
  //                      4.19M) -- dead after GEMM2; S2 (fp16, 16.78M)
  //                      ALIASES this region (stream-sequential safe).
  //   [16.78M, 50.33M) : bufI (fp32, 33.55M)
  //   [50.33M, 67.11M) : S1 (fp16, 16.78M)
  //   [67.11M, 67.44M) : buf3 (fp32, 0.33M)
  char* base = (char*)d_ws;
  const long S2_BYTES = (long)TM * TH * 2;  // 16,777,216
  f16_t* W1p  = (f16_t*)base;
  f16_t* W2p  = (f16_t*)(base + 2L * TH * KP1 * 2);  // after 9,699,328 B
  float* bufI = (float*)(base + S2_BYTES);
  f16_t* S1   = (f16_t*)(base + S2_BYTES + (long)TM * TH * 4);
  float* buf3 = (float*)(base + S2_BYTES + (long)TM * TH * 4 + (long)TM * TH * 2);
  f16_t* S2   = (f16_t*)base;

  split_w1h<<<dim3(3, TH), 256, 0, stream>>>(W1, W1p, (long)TH * KP1, TIN, KP1);
  split_w1h<<<dim3(1, TH), 256, 0, stream>>>(W2, W2p, (long)TH * TH, TH, TH);

  // GEMM1: row r=(t,b): x offset = t*2312 + b*(32*2312)
  snn_gemm1<<<dim3(TM / 128, TH / 128), 512, 0, stream>>>(
      x, (long)TIN, (long)TT * TIN, W1p, (long)TH * KP1, KP1, TIN, b1, bufI,
      TH);

  lif_scan_f16<<<(TB * TH) / 256, 256, 0, stream>>>(bufI, S1);

  // GEMM2: S1 row-major [8192][1024]: sT=256*1024, sB=1024
  snn_gemm2<<<dim3(TM / 128, TH / 128), 512, 0, stream>>>(
      S1, (long)TB * TH, (long)TH, W2p, (long)TH * TH, TH, b2, bufI, TH);

  lif_scan_f16<<<(TB * TH) / 256, 256, 0, stream>>>(bufI, S2);

  gemm3_kernel<<<(TM * 64) / 256, 256, 0, stream>>>(S2, Wout, bout, buf3);

  scan_out<<<(TB * TOUT + 255) / 256, 256, 0, stream>>>(buf3, (float*)d_out);
}

// Round 11
// 315.433 us; speedup vs baseline: 3.6107x; 1.0209x over previous
//
#include <hip/hip_runtime.h>

// SNN: 3-layer LIF, B=256, T=32, H=1024, IN=2312, OUT=10.
// Ledger: r2 skeleton (2-barrier, LDW pad, 16 waves/CU) G1=153.9us;
//   r6 skeleton (1-barrier, fragment-LDS conflict-free, gload_lds B) G1=164us
//   at only 8 waves/CU -- ~1.9x better per-wave efficiency, wave-starved
//   (LDS ~41% busy). Round-14: r6 structure re-partitioned to 512-thread
//   blocks (8 waves 4Mx2N of 32x64) -> 64KB LDS, 2 blk/CU, 16 waves/CU.
//   One barrier/tile, no B-commit VALU, conflict-free fragment reads.
//   G2 same skeleton: 1 A-plane -> 48KB LDS -> 3 blk/CU = 24 waves/CU.
//   All pieces separately verified (frag planes r7-r9, 1-barrier loop r8/r9,
//   mblk-fast grid r6, split-3-pass math r2) -- recombination only.

#define TB 256
#define TT 32
#define TH 1024
#define TIN 2312
#define TOUT 10
#define TM (TT * TB)   // 8192 rows = (t,b)
#define NK1 74         // K-tiles of 32 for GEMM1 (2368 = 74*32)
#define NK2 32         // K-tiles for GEMM2 (1024)
#define FR 512         // f16 elems per (16 x 32) fragment

typedef _Float16 f16_t;
typedef f16_t f16x8 __attribute__((ext_vector_type(8)));
typedef float floatx4 __attribute__((ext_vector_type(4)));

__device__ __forceinline__ void split2h(float v, f16_t& a, f16_t& b) {
  a = (f16_t)v;
  b = (f16_t)(v - (float)a);
}

// async 16B global->LDS; LDS dest = wave-uniform base + lane*16.
__device__ __forceinline__ void gload16(const void* g, void* l) {
  __builtin_amdgcn_global_load_lds(
      (const __attribute__((address_space(1))) void*)g,
      (__attribute__((address_space(3))) void*)l, 16, 0, 0);
}

// W (N x K) -> 2 fp16 planes in MFMA-B-fragment order:
// P[q*plane + fid*512 + lane*8 + e] =
//   split_q(W[(n16*16 + (lane&15))*K + k32*32 + (lane>>4)*8 + e]),
// fid = n16*nk32 + k32, zero for k >= K. (Verified absmax 0.0, r7-r9.)
__global__ __launch_bounds__(256) void split_w_frag(
    const float* __restrict__ W, f16_t* __restrict__ P, long plane,
    int K, int nk32) {
  const int fid = blockIdx.x * 4 + (threadIdx.x >> 6);
  const int lane = threadIdx.x & 63;
  const int n16 = fid / nk32, k32 = fid - n16 * nk32;
  const long row = n16 * 16 + (lane & 15);
  const int k0 = k32 * 32 + (lane >> 4) * 8;
  float t[8];
  if (k0 + 8 <= K) {
    float4 v0 = *(const float4*)(W + row * K + k0);
    float4 v1 = *(const float4*)(W + row * K + k0 + 4);
    t[0] = v0.x; t[1] = v0.y; t[2] = v0.z; t[3] = v0.w;
    t[4] = v1.x; t[5] = v1.y; t[6] = v1.z; t[7] = v1.w;
  } else {
    #pragma unroll
    for (int e = 0; e < 8; ++e) t[e] = 0.f;
  }
  f16x8 h0, h1;
  #pragma unroll
  for (int e = 0; e < 8; ++e) {
    f16_t a, b;
    split2h(t[e], a, b);
    h0[e] = a; h1[e] = b;
  }
  const long o = (long)fid * 512 + lane * 8;
  *(f16x8*)(P + o) = h0;
  *(f16x8*)(P + plane + o) = h1;
}

// GEMM1: 3 fp16 passes (a0b0, a1b0, a0b1); A = x fp32 split in-kernel,
// B = W1 fragment planes via global_load_lds. ONE barrier per K-tile.
// 512 thr = 8 waves 4(M)x2(N), per-wave 32x64. Grid dim3(64,8) mblk-fast.
__global__ __launch_bounds__(512, 4) void snn_gemm1(
    const float* __restrict__ Af, long sT, long sB,
    const f16_t* __restrict__ Bf, long planeB, int nk32, int K,
    const float* __restrict__ bias, float* __restrict__ C, int N) {
  __shared__ f16_t As[2 * 2 * 8 * FR];  // [buf][plane][m16][512]  32 KB
  __shared__ f16_t Bs[2 * 2 * 8 * FR];  // [buf][plane][n16][512]  32 KB

  const int tid = threadIdx.x;
  const int wave = tid >> 6, lane = tid & 63;
  const int quad = lane >> 4, l16 = lane & 15;
  const int wm = (wave & 3) * 32, wn = (wave >> 2) * 64;
  const int a16 = (wave & 3) * 2, b16 = (wave >> 2) * 4;  // frag bases
  const long m0 = (long)blockIdx.x * 128, n0 = (long)blockIdx.y * 128;

  floatx4 acc[2][4];
  #pragma unroll
  for (int i = 0; i < 2; ++i)
    #pragma unroll
    for (int j = 0; j < 4; ++j) acc[i][j] = (floatx4){0.f, 0.f, 0.f, 0.f};

  // A staging: thread owns (row cr, 8-elem k-seg csg): 8 fp32 -> 2 frags
  const int cr = tid >> 2, csg = tid & 3;
  const int am16 = cr >> 4;
  const int lnA = (cr & 15) | (csg << 4);
  const float* xrow = Af + ((m0 + cr) >> 8) * sT + ((m0 + cr) & 255) * sB;

  float4 xv[2];
  auto prefetchA = [&](int kt) {
    const int k0 = kt * 32 + csg * 8;
    xv[0] = (k0 < K) ? *(const float4*)(xrow + k0) : float4{0.f, 0.f, 0.f, 0.f};
    xv[1] = (k0 + 4 < K) ? *(const float4*)(xrow + k0 + 4)
                         : float4{0.f, 0.f, 0.f, 0.f};
  };

  auto commitA = [&](int buf) {
    float t[8] = {xv[0].x, xv[0].y, xv[0].z, xv[0].w,
                  xv[1].x, xv[1].y, xv[1].z, xv[1].w};
    f16x8 p0, p1;
    #pragma unroll
    for (int e = 0; e < 8; ++e) {
      f16_t a, b;
      split2h(t[e], a, b);
      p0[e] = a; p1[e] = b;
    }
    *(f16x8*)(&As[((buf * 2 + 0) * 8 + am16) * FR + lnA * 8]) = p0;
    *(f16x8*)(&As[((buf * 2 + 1) * 8 + am16) * FR + lnA * 8]) = p1;
  };

  // B staging: 16 chunks of 1KB (2 planes x 8 n16-frags); wave w does 2.
  const long nbase = (n0 >> 4) * (long)nk32;
  auto gloadB = [&](int kt, int buf) {
    #pragma unroll
    for (int c = 0; c < 2; ++c) {
      const int chk = wave * 2 + c;
      const int pl = chk >> 3, n16 = chk & 7;
      const f16_t* src = Bf + pl * planeB +
                         (nbase + (long)n16 * nk32 + kt) * FR + lane * 8;
      gload16(src, &Bs[((buf * 2 + pl) * 8 + n16) * FR]);
    }
  };

  // prologue: tile0 staged; xv <- A(1)
  prefetchA(0);
  gloadB(0, 0);
  commitA(0);
  prefetchA(1);
  __syncthreads();  // drains gloadB(0); commit(0) visible

  for (int kt = 0; kt < nk32; ++kt) {
    const int cur = kt & 1;
    // invariant: As/Bs[cur] ready; xv = A(kt+1)
    if (kt + 1 < nk32) {
      gloadB(kt + 1, cur ^ 1);  // in flight across this MFMA phase
      commitA(cur ^ 1);         // xv already arrived (prev barrier drained)
    }
    if (kt + 2 < nk32) prefetchA(kt + 2);

    f16x8 afr[2][2];
    #pragma unroll
    for (int pl = 0; pl < 2; ++pl)
      #pragma unroll
      for (int i = 0; i < 2; ++i)
        afr[pl][i] = *(const f16x8*)(
            &As[((cur * 2 + pl) * 8 + a16 + i) * FR + lane * 8]);

    #pragma unroll
    for (int pb = 0; pb < 2; ++pb) {
      f16x8 bfr[4];
      #pragma unroll
      for (int j = 0; j < 4; ++j)
        bfr[j] = *(const f16x8*)(
            &Bs[((cur * 2 + pb) * 8 + b16 + j) * FR + lane * 8]);
      const int pamax = 1 - pb;  // passes (0,0),(1,0),(0,1)
      #pragma unroll
      for (int pa = 0; pa < 2; ++pa) {
        if (pa > pamax) break;
        #pragma unroll
        for (int i = 0; i < 2; ++i)
          #pragma unroll
          for (int j = 0; j < 4; ++j)
            acc[i][j] = __builtin_amdgcn_mfma_f32_16x16x32_f16(
                afr[pa][i], bfr[j], acc[i][j], 0, 0, 0);
      }
    }
    __syncthreads();  // frag reads done; gloadB(kt+1)/commit drained+visible
  }

  // epilogue: C/D layout col=lane&15, row=quad*4+reg (verified)
  #pragma unroll
  for (int j = 0; j < 4; ++j) {
    const long col = n0 + wn + j * 16 + l16;
    const float bvv = bias[col];
    #pragma unroll
    for (int i = 0; i < 2; ++i) {
      const long row0 = m0 + wm + i * 16 + quad * 4;
      #pragma unroll
      for (int g = 0; g < 4; ++g)
        C[(row0 + g) * (long)N + col] = acc[i][j][g] + bvv;
    }
  }
}

// GEMM2: A = spikes (fp16 exact, 1 plane), B = W2 frag planes via
// global_load_lds, 2 passes (a*(b0+b1), nothing dropped). Same skeleton;
// LDS 48KB -> 3 blocks/CU.
__global__ __launch_bounds__(512, 4) void snn_gemm2(
    const f16_t* __restrict__ Ab, long sT, long sB,
    const f16_t* __restrict__ Bf, long planeB, int nk32,
    const float* __restrict__ bias, float* __restrict__ C, int N) {
  __shared__ f16_t As[2 * 8 * FR];      // [buf][m16][512]  16 KB
  __shared__ f16_t Bs[2 * 2 * 8 * FR];  // 32 KB

  const int tid = threadIdx.x;
  const int wave = tid >> 6, lane = tid & 63;
  const int quad = lane >> 4, l16 = lane & 15;
  const int wm = (wave & 3) * 32, wn = (wave >> 2) * 64;
  const int a16 = (wave & 3) * 2, b16 = (wave >> 2) * 4;
  const long m0 = (long)blockIdx.x * 128, n0 = (long)blockIdx.y * 128;

  floatx4 acc[2][4];
  #pragma unroll
  for (int i = 0; i < 2; ++i)
    #pragma unroll
    for (int j = 0; j < 4; ++j) acc[i][j] = (floatx4){0.f, 0.f, 0.f, 0.f};

  const int cr = tid >> 2, csg = tid & 3;
  const int am16 = cr >> 4;
  const int lnA = (cr & 15) | (csg << 4);
  const f16_t* arow = Ab + ((m0 + cr) >> 8) * sT + ((m0 + cr) & 255) * sB;

  f16x8 av;
  auto prefetchA = [&](int kt) {
    av = *(const f16x8*)(arow + kt * 32 + csg * 8);
  };

  auto commitA = [&](int buf) {
    *(f16x8*)(&As[(buf * 8 + am16) * FR + lnA * 8]) = av;
  };

  const long nbase = (n0 >> 4) * (long)nk32;
  auto gloadB = [&](int kt, int buf) {
    #pragma unroll
    for (int c = 0; c < 2; ++c) {
      const int chk = wave * 2 + c;
      const int pl = chk >> 3, n16 = chk & 7;
      const f16_t* src = Bf + pl * planeB +
                         (nbase + (long)n16 * nk32 + kt) * FR + lane * 8;
      gload16(src, &Bs[((buf * 2 + pl) * 8 + n16) * FR]);
    }
  };

  prefetchA(0);
  gloadB(0, 0);
  commitA(0);
  prefetchA(1);
  __syncthreads();

  for (int kt = 0; kt < nk32; ++kt) {
    const int cur = kt & 1;
    if (kt + 1 < nk32) {
      gloadB(kt + 1, cur ^ 1);
      commitA(cur ^ 1);
    }
    if (kt + 2 < nk32) prefetchA(kt + 2);

    f16x8 afr[2];
    #pragma unroll
    for (int i = 0; i < 2; ++i)
      afr[i] = *(const f16x8*)(&As[(cur * 8 + a16 + i) * FR + lane * 8]);

    #pragma unroll
    for (int pb = 0; pb < 2; ++pb) {
      f16x8 bfr[4];
      #pragma unroll
      for (int j = 0; j < 4; ++j)
        bfr[j] = *(const f16x8*)(
            &Bs[((cur * 2 + pb) * 8 + b16 + j) * FR + lane * 8]);
      #pragma unroll
      for (int i = 0; i < 2; ++i)
        #pragma unroll
        for (int j = 0; j < 4; ++j)
          acc[i][j] = __builtin_amdgcn_mfma_f32_16x16x32_f16(
              afr[i], bfr[j], acc[i][j], 0, 0, 0);
    }
    __syncthreads();
  }

  #pragma unroll
  for (int j = 0; j < 4; ++j) {
    const long col = n0 + wn + j * 16 + l16;
    const float bvv = bias[col];
    #pragma unroll
    for (int i = 0; i < 2; ++i) {
      const long row0 = m0 + wm + i * 16 + quad * 4;
      #pragma unroll
      for (int g = 0; g < 4; ++g)
        C[(row0 + g) * (long)N + col] = acc[i][j][g] + bvv;
    }
  }
}

// LIF scan, fp32 in -> fp16 spikes out (spikes {0,1} exact in fp16).
__global__ __launch_bounds__(256) void lif_scan_f16(const float* __restrict__ I,
                                                    f16_t* __restrict__ S) {
  int idx = blockIdx.x * 256 + threadIdx.x;
  float v = 0.f, cur = 0.f;
  #pragma unroll
  for (int t = 0; t < TT; ++t) {
    float inp = I[(long)t * (TB * TH) + idx];
    float vd = fmaf(0.05f, cur - v, v);
    float id = cur - 0.2f * cur;
    float s = (vd > 1.0f) ? 1.0f : 0.f;
    v = (1.0f - s) * vd;
    cur = id + inp;
    S[(long)t * (TB * TH) + idx] = (f16_t)s;
  }
}

// GEMM3: one wave per row; I3[r][o] = S2[r][:] . Wout[o][:] + bout[o]
__global__ __launch_bounds__(256) void gemm3_kernel(
    const f16_t* __restrict__ S2, const float* __restrict__ Wout,
    const float* __restrict__ bout, float* __restrict__ I3) {
  int wv = (blockIdx.x * blockDim.x + threadIdx.x) >> 6;
  int lane = threadIdx.x & 63;
  if (wv >= TM) return;
  const f16_t* srow = S2 + (long)wv * TH;
  float acc[TOUT];
  #pragma unroll
  for (int o = 0; o < TOUT; ++o) acc[o] = 0.f;
  for (int k = lane; k < TH; k += 64) {
    float s = (float)srow[k];
    #pragma unroll
    for (int o = 0; o < TOUT; ++o) acc[o] = fmaf(s, Wout[o * TH + k], acc[o]);
  }
  #pragma unroll
  for (int off = 32; off > 0; off >>= 1)
    #pragma unroll
    for (int o = 0; o < TOUT; ++o) acc[o] += __shfl_down(acc[o], off, 64);
  if (lane == 0) {
    #pragma unroll
    for (int o = 0; o < TOUT; ++o) I3[(long)wv * TOUT + o] = acc[o] + bout[o];
  }
}

__global__ __launch_bounds__(256) void scan_out(const float* __restrict__ I3,
                                                float* __restrict__ out) {
  int idx = blockIdx.x * blockDim.x + threadIdx.x;
  if (idx >= TB * TOUT) return;
  float v = 0.f, cur = 0.f, cnt = 0.f;
  #pragma unroll
  for (int t = 0; t < TT; ++t) {
    float inp = I3[(long)t * (TB * TOUT) + idx];
    float vd = fmaf(0.05f, cur - v, v);
    float id = cur - 0.2f * cur;
    float s = (vd > 1.0f) ? 1.0f : 0.f;
    v = (1.0f - s) * vd;
    cur = id + inp;
    cnt += s;
  }
  out[idx] = cnt;
}

extern "C" void kernel_launch(void* const* d_in, const int* in_sizes, int n_in,
                              void* d_out, int out_size, void* d_ws,
                              size_t ws_size, hipStream_t stream) {
  const float* x    = (const float*)d_in[0];  // (256,32,2312)
  const float* W1   = (const float*)d_in[1];  // (1024,2312)
  const float* b1   = (const float*)d_in[2];
  const float* W2   = (const float*)d_in[3];  // (1024,1024)
  const float* b2   = (const float*)d_in[4];
  const float* Wout = (const float*)d_in[5];  // (10,1024)
  const float* bout = (const float*)d_in[6];

  // Fragment-plane sizes (elements): W1 64 n16 x 74 k32 x 512 = 2,424,832;
  // W2 64 x 32 x 512 = 1,048,576.
  const long PL1 = 64L * NK1 * 512;
  const long PL2 = 64L * NK2 * 512;

  // ws layout (bytes):
  //   [0, 16.78M)      : W1p (2 planes, 9.70M) + W2p (2 planes, 4.19M) --
  //                      dead after GEMM2; S2 (fp16, 16.78M) ALIASES this
  //                      region (stream-sequential safe; rebuilt each call).
  //   [16.78M, 50.33M) : bufI (fp32, 33.55M)
  //   [50.33M, 67.11M) : S1 (fp16, 16.78M)
  //   [67.11M, 67.44M) : buf3 (fp32, 0.33M)
  char* base = (char*)d_ws;
  const long S2_BYTES = (long)TM * TH * 2;  // 16,777,216
  f16_t* W1p  = (f16_t*)base;
  f16_t* W2p  = (f16_t*)(base + 2 * PL1 * 2);  // after 9,699,328 B
  float* bufI = (float*)(base + S2_BYTES);
  f16_t* S1   = (f16_t*)(base + S2_BYTES + (long)TM * TH * 4);
  float* buf3 = (float*)(base + S2_BYTES + (long)TM * TH * 4 + (long)TM * TH * 2);
  f16_t* S2   = (f16_t*)base;

  split_w_frag<<<64 * NK1 / 4, 256, 0, stream>>>(W1, W1p, PL1, TIN, NK1);
  split_w_frag<<<64 * NK2 / 4, 256, 0, stream>>>(W2, W2p, PL2, TH, NK2);

  // GEMM1: row r=(t,b): x offset = t*2312 + b*(32*2312)
  snn_gemm1<<<dim3(64, 8), 512, 0, stream>>>(
      x, (long)TIN, (long)TT * TIN, W1p, PL1, NK1, TIN, b1, bufI, TH);

  lif_scan_f16<<<(TB * TH) / 256, 256, 0, stream>>>(bufI, S1);

  // GEMM2: S1 row-major [8192][1024]: sT=256*1024, sB=1024
  snn_gemm2<<<dim3(64, 8), 512, 0, stream>>>(
      S1, (long)TB * TH, (long)TH, W2p, PL2, NK2, b2, bufI, TH);

  lif_scan_f16<<<(TB * TH) / 256, 256, 0, stream>>>(bufI, S2);

  gemm3_kernel<<<(TM * 64) / 256, 256, 0, stream>>>(S2, Wout, bout, buf3);

  scan_out<<<(TB * TOUT + 255) / 256, 256, 0, stream>>>(buf3, (float*)d_out);
}

// Round 12
// 313.361 us; speedup vs baseline: 3.6346x; 1.0066x over previous
//
#include <hip/hip_runtime.h>

// SNN: 3-layer LIF, B=256, T=32, H=1024, IN=2312, OUT=10.
// r11 (best, 315us): r6 structure at 16 waves/CU -- 1 barrier/tile,
//   fragment-order LDS, gload_lds B, fp16 2-plane (G1 3-pass, G2 2-pass).
//   G1=148us, LDS ~80% busy => binding pipe. Conflict counter 14.55M =
//   commitA ds_writes: bank-group 4*(cr&7), csg invisible -> 4-way per
//   16-lane phase (606k writes x ~24cyc matches counter exactly).
// Round-15: XOR-swizzle A granules (reg-staged side only; B stays linear
//   per both-sides-or-neither rule): store granule g at g^((g>>4)<<1).
//   Write pos = lnA ^ (csg<<1): phase bank-groups become 2-way (free).
//   Read pos = lane ^ ((lane>>4)<<1): bijection per 16-block, 2-way free.
//   Applied to As in both GEMMs. Everything else byte-identical to r11.

#define TB 256
#define TT 32
#define TH 1024
#define TIN 2312
#define TOUT 10
#define TM (TT * TB)   // 8192 rows = (t,b)
#define NK1 74         // K-tiles of 32 for GEMM1 (2368 = 74*32)
#define NK2 32         // K-tiles for GEMM2 (1024)
#define FR 512         // f16 elems per (16 x 32) fragment

typedef _Float16 f16_t;
typedef f16_t f16x8 __attribute__((ext_vector_type(8)));
typedef float floatx4 __attribute__((ext_vector_type(4)));

__device__ __forceinline__ void split2h(float v, f16_t& a, f16_t& b) {
  a = (f16_t)v;
  b = (f16_t)(v - (float)a);
}

// async 16B global->LDS; LDS dest = wave-uniform base + lane*16.
__device__ __forceinline__ void gload16(const void* g, void* l) {
  __builtin_amdgcn_global_load_lds(
      (const __attribute__((address_space(1))) void*)g,
      (__attribute__((address_space(3))) void*)l, 16, 0, 0);
}

// W (N x K) -> 2 fp16 planes in MFMA-B-fragment order:
// P[q*plane + fid*512 + lane*8 + e] =
//   split_q(W[(n16*16 + (lane&15))*K + k32*32 + (lane>>4)*8 + e]),
// fid = n16*nk32 + k32, zero for k >= K. (Verified absmax 0.0, r7-r11.)
__global__ __launch_bounds__(256) void split_w_frag(
    const float* __restrict__ W, f16_t* __restrict__ P, long plane,
    int K, int nk32) {
  const int fid = blockIdx.x * 4 + (threadIdx.x >> 6);
  const int lane = threadIdx.x & 63;
  const int n16 = fid / nk32, k32 = fid - n16 * nk32;
  const long row = n16 * 16 + (lane & 15);
  const int k0 = k32 * 32 + (lane >> 4) * 8;
  float t[8];
  if (k0 + 8 <= K) {
    float4 v0 = *(const float4*)(W + row * K + k0);
    float4 v1 = *(const float4*)(W + row * K + k0 + 4);
    t[0] = v0.x; t[1] = v0.y; t[2] = v0.z; t[3] = v0.w;
    t[4] = v1.x; t[5] = v1.y; t[6] = v1.z; t[7] = v1.w;
  } else {
    #pragma unroll
    for (int e = 0; e < 8; ++e) t[e] = 0.f;
  }
  f16x8 h0, h1;
  #pragma unroll
  for (int e = 0; e < 8; ++e) {
    f16_t a, b;
    split2h(t[e], a, b);
    h0[e] = a; h1[e] = b;
  }
  const long o = (long)fid * 512 + lane * 8;
  *(f16x8*)(P + o) = h0;
  *(f16x8*)(P + plane + o) = h1;
}

// GEMM1: 3 fp16 passes (a0b0, a1b0, a0b1); A = x fp32 split in-kernel,
// B = W1 fragment planes via global_load_lds. ONE barrier per K-tile.
// 512 thr = 8 waves 4(M)x2(N), per-wave 32x64. Grid dim3(64,8) mblk-fast.
__global__ __launch_bounds__(512, 4) void snn_gemm1(
    const float* __restrict__ Af, long sT, long sB,
    const f16_t* __restrict__ Bf, long planeB, int nk32, int K,
    const float* __restrict__ bias, float* __restrict__ C, int N) {
  __shared__ f16_t As[2 * 2 * 8 * FR];  // [buf][plane][m16][512]  32 KB
  __shared__ f16_t Bs[2 * 2 * 8 * FR];  // [buf][plane][n16][512]  32 KB

  const int tid = threadIdx.x;
  const int wave = tid >> 6, lane = tid & 63;
  const int quad = lane >> 4, l16 = lane & 15;
  const int wm = (wave & 3) * 32, wn = (wave >> 2) * 64;
  const int a16 = (wave & 3) * 2, b16 = (wave >> 2) * 4;  // frag bases
  const long m0 = (long)blockIdx.x * 128, n0 = (long)blockIdx.y * 128;

  floatx4 acc[2][4];
  #pragma unroll
  for (int i = 0; i < 2; ++i)
    #pragma unroll
    for (int j = 0; j < 4; ++j) acc[i][j] = (floatx4){0.f, 0.f, 0.f, 0.f};

  // A staging: thread owns (row cr, 8-elem k-seg csg): 8 fp32 -> 2 frags.
  // Granule swizzle s(g) = g ^ ((g>>4)<<1): write pos lnA^(csg<<1),
  // read pos lane^((lane>>4)<<1) -- breaks the 4-way write conflict.
  const int cr = tid >> 2, csg = tid & 3;
  const int am16 = cr >> 4;
  const int lnA = ((cr & 15) | (csg << 4)) ^ (csg << 1);  // swizzled slot
  const int lnR = lane ^ ((lane >> 4) << 1);              // swizzled read
  const float* xrow = Af + ((m0 + cr) >> 8) * sT + ((m0 + cr) & 255) * sB;

  float4 xv[2];
  auto prefetchA = [&](int kt) {
    const int k0 = kt * 32 + csg * 8;
    xv[0] = (k0 < K) ? *(const float4*)(xrow + k0) : float4{0.f, 0.f, 0.f, 0.f};
    xv[1] = (k0 + 4 < K) ? *(const float4*)(xrow + k0 + 4)
                         : float4{0.f, 0.f, 0.f, 0.f};
  };

  auto commitA = [&](int buf) {
    float t[8] = {xv[0].x, xv[0].y, xv[0].z, xv[0].w,
                  xv[1].x, xv[1].y, xv[1].z, xv[1].w};
    f16x8 p0, p1;
    #pragma unroll
    for (int e = 0; e < 8; ++e) {
      f16_t a, b;
      split2h(t[e], a, b);
      p0[e] = a; p1[e] = b;
    }
    *(f16x8*)(&As[((buf * 2 + 0) * 8 + am16) * FR + lnA * 8]) = p0;
    *(f16x8*)(&As[((buf * 2 + 1) * 8 + am16) * FR + lnA * 8]) = p1;
  };

  // B staging: 16 chunks of 1KB (2 planes x 8 n16-frags); wave w does 2.
  const long nbase = (n0 >> 4) * (long)nk32;
  auto gloadB = [&](int kt, int buf) {
    #pragma unroll
    for (int c = 0; c < 2; ++c) {
      const int chk = wave * 2 + c;
      const int pl = chk >> 3, n16 = chk & 7;
      const f16_t* src = Bf + pl * planeB +
                         (nbase + (long)n16 * nk32 + kt) * FR + lane * 8;
      gload16(src, &Bs[((buf * 2 + pl) * 8 + n16) * FR]);
    }
  };

  // prologue: tile0 staged; xv <- A(1)
  prefetchA(0);
  gloadB(0, 0);
  commitA(0);
  prefetchA(1);
  __syncthreads();  // drains gloadB(0); commit(0) visible

  for (int kt = 0; kt < nk32; ++kt) {
    const int cur = kt & 1;
    // invariant: As/Bs[cur] ready; xv = A(kt+1)
    if (kt + 1 < nk32) {
      gloadB(kt + 1, cur ^ 1);  // in flight across this MFMA phase
      commitA(cur ^ 1);         // xv already arrived (prev barrier drained)
    }
    if (kt + 2 < nk32) prefetchA(kt + 2);

    f16x8 afr[2][2];
    #pragma unroll
    for (int pl = 0; pl < 2; ++pl)
      #pragma unroll
      for (int i = 0; i < 2; ++i)
        afr[pl][i] = *(const f16x8*)(
            &As[((cur * 2 + pl) * 8 + a16 + i) * FR + lnR * 8]);

    #pragma unroll
    for (int pb = 0; pb < 2; ++pb) {
      f16x8 bfr[4];
      #pragma unroll
      for (int j = 0; j < 4; ++j)
        bfr[j] = *(const f16x8*)(
            &Bs[((cur * 2 + pb) * 8 + b16 + j) * FR + lane * 8]);
      const int pamax = 1 - pb;  // passes (0,0),(1,0),(0,1)
      #pragma unroll
      for (int pa = 0; pa < 2; ++pa) {
        if (pa > pamax) break;
        #pragma unroll
        for (int i = 0; i < 2; ++i)
          #pragma unroll
          for (int j = 0; j < 4; ++j)
            acc[i][j] = __builtin_amdgcn_mfma_f32_16x16x32_f16(
                afr[pa][i], bfr[j], acc[i][j], 0, 0, 0);
      }
    }
    __syncthreads();  // frag reads done; gloadB(kt+1)/commit drained+visible
  }

  // epilogue: C/D layout col=lane&15, row=quad*4+reg (verified)
  #pragma unroll
  for (int j = 0; j < 4; ++j) {
    const long col = n0 + wn + j * 16 + l16;
    const float bvv = bias[col];
    #pragma unroll
    for (int i = 0; i < 2; ++i) {
      const long row0 = m0 + wm + i * 16 + quad * 4;
      #pragma unroll
      for (int g = 0; g < 4; ++g)
        C[(row0 + g) * (long)N + col] = acc[i][j][g] + bvv;
    }
  }
}

// GEMM2: A = spikes (fp16 exact, 1 plane), B = W2 frag planes via
// global_load_lds, 2 passes (a*(b0+b1), nothing dropped). Same skeleton;
// LDS 48KB -> 3 blocks/CU. Same A-granule swizzle.
__global__ __launch_bounds__(512, 4) void snn_gemm2(
    const f16_t* __restrict__ Ab, long sT, long sB,
    const f16_t* __restrict__ Bf, long planeB, int nk32,
    const float* __restrict__ bias, float* __restrict__ C, int N) {
  __shared__ f16_t As[2 * 8 * FR];      // [buf][m16][512]  16 KB
  __shared__ f16_t Bs[2 * 2 * 8 * FR];  // 32 KB

  const int tid = threadIdx.x;
  const int wave = tid >> 6, lane = tid & 63;
  const int quad = lane >> 4, l16 = lane & 15;
  const int wm = (wave & 3) * 32, wn = (wave >> 2) * 64;
  const int a16 = (wave & 3) * 2, b16 = (wave >> 2) * 4;
  const long m0 = (long)blockIdx.x * 128, n0 = (long)blockIdx.y * 128;

  floatx4 acc[2][4];
  #pragma unroll
  for (int i = 0; i < 2; ++i)
    #pragma unroll
    for (int j = 0; j < 4; ++j) acc[i][j] = (floatx4){0.f, 0.f, 0.f, 0.f};

  const int cr = tid >> 2, csg = tid & 3;
  const int am16 = cr >> 4;
  const int lnA = ((cr & 15) | (csg << 4)) ^ (csg << 1);  // swizzled slot
  const int lnR = lane ^ ((lane >> 4) << 1);              // swizzled read
  const f16_t* arow = Ab + ((m0 + cr) >> 8) * sT + ((m0 + cr) & 255) * sB;

  f16x8 av;
  auto prefetchA = [&](int kt) {
    av = *(const f16x8*)(arow + kt * 32 + csg * 8);
  };

  auto commitA = [&](int buf) {
    *(f16x8*)(&As[(buf * 8 + am16) * FR + lnA * 8]) = av;
  };

  const long nbase = (n0 >> 4) * (long)nk32;
  auto gloadB = [&](int kt, int buf) {
    #pragma unroll
    for (int c = 0; c < 2; ++c) {
      const int chk = wave * 2 + c;
      const int pl = chk >> 3, n16 = chk & 7;
      const f16_t* src = Bf + pl * planeB +
                         (nbase + (long)n16 * nk32 + kt) * FR + lane * 8;
      gload16(src, &Bs[((buf * 2 + pl) * 8 + n16) * FR]);
    }
  };

  prefetchA(0);
  gloadB(0, 0);
  commitA(0);
  prefetchA(1);
  __syncthreads();

  for (int kt = 0; kt < nk32; ++kt) {
    const int cur = kt & 1;
    if (kt + 1 < nk32) {
      gloadB(kt + 1, cur ^ 1);
      commitA(cur ^ 1);
    }
    if (kt + 2 < nk32) prefetchA(kt + 2);

    f16x8 afr[2];
    #pragma unroll
    for (int i = 0; i < 2; ++i)
      afr[i] = *(const f16x8*)(&As[(cur * 8 + a16 + i) * FR + lnR * 8]);

    #pragma unroll
    for (int pb = 0; pb < 2; ++pb) {
      f16x8 bfr[4];
      #pragma unroll
      for (int j = 0; j < 4; ++j)
        bfr[j] = *(const f16x8*)(
            &Bs[((cur * 2 + pb) * 8 + b16 + j) * FR + lane * 8]);
      #pragma unroll
      for (int i = 0; i < 2; ++i)
        #pragma unroll
        for (int j = 0; j < 4; ++j)
          acc[i][j] = __builtin_amdgcn_mfma_f32_16x16x32_f16(
              afr[i], bfr[j], acc[i][j], 0, 0, 0);
    }
    __syncthreads();
  }

  #pragma unroll
  for (int j = 0; j < 4; ++j) {
    const long col = n0 + wn + j * 16 + l16;
    const float bvv = bias[col];
    #pragma unroll
    for (int i = 0; i < 2; ++i) {
      const long row0 = m0 + wm + i * 16 + quad * 4;
      #pragma unroll
      for (int g = 0; g < 4; ++g)
        C[(row0 + g) * (long)N + col] = acc[i][j][g] + bvv;
    }
  }
}

// LIF scan, fp32 in -> fp16 spikes out (spikes {0,1} exact in fp16).
__global__ __launch_bounds__(256) void lif_scan_f16(const float* __restrict__ I,
                                                    f16_t* __restrict__ S) {
  int idx = blockIdx.x * 256 + threadIdx.x;
  float v = 0.f, cur = 0.f;
  #pragma unroll
  for (int t = 0; t < TT; ++t) {
    float inp = I[(long)t * (TB * TH) + idx];
    float vd = fmaf(0.05f, cur - v, v);
    float id = cur - 0.2f * cur;
    float s = (vd > 1.0f) ? 1.0f : 0.f;
    v = (1.0f - s) * vd;
    cur = id + inp;
    S[(long)t * (TB * TH) + idx] = (f16_t)s;
  }
}

// GEMM3: one wave per row; I3[r][o] = S2[r][:] . Wout[o][:] + bout[o]
__global__ __launch_bounds__(256) void gemm3_kernel(
    const f16_t* __restrict__ S2, const float* __restrict__ Wout,
    const float* __restrict__ bout, float* __restrict__ I3) {
  int wv = (blockIdx.x * blockDim.x + threadIdx.x) >> 6;
  int lane = threadIdx.x & 63;
  if (wv >= TM) return;
  const f16_t* srow = S2 + (long)wv * TH;
  float acc[TOUT];
  #pragma unroll
  for (int o = 0; o < TOUT; ++o) acc[o] = 0.f;
  for (int k = lane; k < TH; k += 64) {
    float s = (float)srow[k];
    #pragma unroll
    for (int o = 0; o < TOUT; ++o) acc[o] = fmaf(s, Wout[o * TH + k], acc[o]);
  }
  #pragma unroll
  for (int off = 32; off > 0; off >>= 1)
    #pragma unroll
    for (int o = 0; o < TOUT; ++o) acc[o] += __shfl_down(acc[o], off, 64);
  if (lane == 0) {
    #pragma unroll
    for (int o = 0; o < TOUT; ++o) I3[(long)wv * TOUT + o] = acc[o] + bout[o];
  }
}

__global__ __launch_bounds__(256) void scan_out(const float* __restrict__ I3,
                                                float* __restrict__ out) {
  int idx = blockIdx.x * blockDim.x + threadIdx.x;
  if (idx >= TB * TOUT) return;
  float v = 0.f, cur = 0.f, cnt = 0.f;
  #pragma unroll
  for (int t = 0; t < TT; ++t) {
    float inp = I3[(long)t * (TB * TOUT) + idx];
    float vd = fmaf(0.05f, cur - v, v);
    float id = cur - 0.2f * cur;
    float s = (vd > 1.0f) ? 1.0f : 0.f;
    v = (1.0f - s) * vd;
    cur = id + inp;
    cnt += s;
  }
  out[idx] = cnt;
}

extern "C" void kernel_launch(void* const* d_in, const int* in_sizes, int n_in,
                              void* d_out, int out_size, void* d_ws,
                              size_t ws_size, hipStream_t stream) {
  const float* x    = (const float*)d_in[0];  // (256,32,2312)
  const float* W1   = (const float*)d_in[1];  // (1024,2312)
  const float* b1   = (const float*)d_in[2];
  const float* W2   = (const float*)d_in[3];  // (1024,1024)
  const float* b2   = (const float*)d_in[4];
  const float* Wout = (const float*)d_in[5];  // (10,1024)
  const float* bout = (const float*)d_in[6];

  // Fragment-plane sizes (elements): W1 64 n16 x 74 k32 x 512 = 2,424,832;
  // W2 64 x 32 x 512 = 1,048,576.
  const long PL1 = 64L * NK1 * 512;
  const long PL2 = 64L * NK2 * 512;

  // ws layout (bytes):
  //   [0, 16.78M)      : W1p (2 planes, 9.70M) + W2p (2 planes, 4.19M) --
  //                      dead after GEMM2; S2 (fp16, 16.78M) ALIASES this
  //                      region (stream-sequential safe; rebuilt each call).
  //   [16.78M, 50.33M) : bufI (fp32, 33.55M)
  //   [50.33M, 67.11M) : S1 (fp16, 16.78M)
  //   [67.11M, 67.44M) : buf3 (fp32, 0.33M)
  char* base = (char*)d_ws;
  const long S2_BYTES = (long)TM * TH * 2;  // 16,777,216
  f16_t* W1p  = (f16_t*)base;
  f16_t* W2p  = (f16_t*)(base + 2 * PL1 * 2);  // after 9,699,328 B
  float* bufI = (float*)(base + S2_BYTES);
  f16_t* S1   = (f16_t*)(base + S2_BYTES + (long)TM * TH * 4);
  float* buf3 = (float*)(base + S2_BYTES + (long)TM * TH * 4 + (long)TM * TH * 2);
  f16_t* S2   = (f16_t*)base;

  split_w_frag<<<64 * NK1 / 4, 256, 0, stream>>>(W1, W1p, PL1, TIN, NK1);
  split_w_frag<<<64 * NK2 / 4, 256, 0, stream>>>(W2, W2p, PL2, TH, NK2);

  // GEMM1: row r=(t,b): x offset = t*2312 + b*(32*2312)
  snn_gemm1<<<dim3(64, 8), 512, 0, stream>>>(
      x, (long)TIN, (long)TT * TIN, W1p, PL1, NK1, TIN, b1, bufI, TH);

  lif_scan_f16<<<(TB * TH) / 256, 256, 0, stream>>>(bufI, S1);

  // GEMM2: S1 row-major [8192][1024]: sT=256*1024, sB=1024
  snn_gemm2<<<dim3(64, 8), 512, 0, stream>>>(
      S1, (long)TB * TH, (long)TH, W2p, PL2, NK2, b2, bufI, TH);

  lif_scan_f16<<<(TB * TH) / 256, 256, 0, stream>>>(bufI, S2);

  gemm3_kernel<<<(TM * 64) / 256, 256, 0, stream>>>(S2, Wout, bout, buf3);

  scan_out<<<(TB * TOUT + 255) / 256, 256, 0, stream>>>(buf3, (float*)d_out);
}